// Round 13
// baseline (284.149 us; speedup 1.0000x reference)
//
#include <hip/hip_runtime.h>
#include <cstddef>

// MPS classifier: SIZE=784, D=32, DLOC=2, NUM_LABELS=10, LABEL_SITE=392, B=128
//
// Round-13: fused single REGULAR kernel with manual device-scope barriers.
//  r12's hipLaunchCooperativeKernel never launched (absmax 33.75 == round-0
//  empty-kernel signature => out never written; coop occupancy check rejected
//  the launch and the error was dropped). Co-residency for 512 blocks is
//  provable without the coop API: LDS 36,864B -> 4 blk/CU; launch_bounds
//  (512,4) -> VGPR<=128 -> 2 blk/CU; grid 512 = 2*256 -> ALL resident.
//  - Barrier 1 (xform->kchain): threadfence (agent) + atomicAdd + bounded
//    spin + threadfence. Device-scope atomics are XCD-coherent.
//  - Barrier 2 (kchain->gfin): last-arrival per batch: 4 producer blocks
//    atomicAdd ctr[b]; winner (old==3) acquires and runs gfin for batch b.
//  - gfin is LDS-free (register label contraction + shfl reduce): the lone
//    wave needs no barrier. Phase bodies otherwise r9-VERBATIM (verified).
// ws: [core2b 3.2MB][halfbuf 2MB][ctrs 516B]. Counters zeroed by a
// hipMemsetAsync node each launch (poison-proof).

typedef short bfrag __attribute__((ext_vector_type(4)));   // 4 bf16
typedef float facc  __attribute__((ext_vector_type(4)));   // 4 fp32

#if !defined(__HIP_DEVICE_COMPILE__)
#define MFMA16(a, b, c) (c)  // host-pass stub (host clang lacks amdgcn builtins)
#elif __has_builtin(__builtin_amdgcn_mfma_f32_16x16x16bf16_1k)
#define MFMA16(a, b, c) __builtin_amdgcn_mfma_f32_16x16x16bf16_1k(a, b, c, 0, 0, 0)
#elif __has_builtin(__builtin_amdgcn_mfma_f32_16x16x16_bf16)
#define MFMA16(a, b, c) __builtin_amdgcn_mfma_f32_16x16x16_bf16(a, b, c, 0, 0, 0)
#else
#error "no 16x16x16 bf16 MFMA builtin on this target"
#endif

#if defined(__HIP_DEVICE_COMPILE__)
#define S_SLEEP() __builtin_amdgcn_s_sleep(2)
#else
#define S_SLEEP()
#endif

#define CORE2B_DWORDS (784 * 1024)
#define HALF_FLOATS (512 * 1024)
#define CTR_DWORD_OFF (CORE2B_DWORDS + HALF_FLOATS)
#define NBLK 512u

__device__ __forceinline__ short bf16h(float v) {
  unsigned u = __float_as_uint(v) + 0x8000u;  // round-half-up to bf16
  return (short)(u >> 16);
}

// pack 4 fp32 -> 4 bf16 (HW cvt_pk on gfx950, manual fallback)
#if defined(__HIP_DEVICE_COMPILE__) && __has_builtin(__builtin_amdgcn_cvt_pk_bf16_f32)
typedef __bf16 bf16x2 __attribute__((ext_vector_type(2)));
__device__ __forceinline__ bfrag packf4(float a, float b, float c, float d) {
  bf16x2 lo = __builtin_amdgcn_cvt_pk_bf16_f32(a, b);
  bf16x2 hi = __builtin_amdgcn_cvt_pk_bf16_f32(c, d);
  uint2 u = make_uint2(__builtin_bit_cast(unsigned, lo), __builtin_bit_cast(unsigned, hi));
  return __builtin_bit_cast(bfrag, u);
}
#else
__device__ __forceinline__ bfrag packf4(float a, float b, float c, float d) {
  bfrag r; r[0] = bf16h(a); r[1] = bf16h(b); r[2] = bf16h(c); r[3] = bf16h(d);
  return r;
}
#endif

__device__ __forceinline__ bfrag pack4(const facc v) {
  return packf4(v[0], v[1], v[2], v[3]);
}

// fp32 -> (hi bf16 rounded, lo bf16 of remainder) — folds only
__device__ __forceinline__ void split4(const float* v, bfrag& hi, bfrag& lo) {
#pragma unroll
  for (int j = 0; j < 4; ++j) {
    unsigned u = (__float_as_uint(v[j]) + 0x8000u) & 0xFFFF0000u;
    hi[j] = (short)(u >> 16);
    float lf = v[j] - __uint_as_float(u);
    lo[j] = bf16h(lf);
  }
}

// One fold step: acc <- A * acc (3-term bf16 hi/lo split).
// av[R][H] = float4 A-frag: A[16R+col16][16H+4q .. +3].
__device__ __forceinline__ void fold_step(facc (&acc)[2][2], const float4 (&av)[2][2]) {
  bfrag Ahi[2][2], Alo[2][2], Bhi[2][2], Blo[2][2];
#pragma unroll
  for (int R = 0; R < 2; ++R)
#pragma unroll
    for (int H = 0; H < 2; ++H) {
      float v[4] = {av[R][H].x, av[R][H].y, av[R][H].z, av[R][H].w};
      split4(v, Ahi[R][H], Alo[R][H]);
    }
#pragma unroll
  for (int H = 0; H < 2; ++H)
#pragma unroll
    for (int c = 0; c < 2; ++c) {
      float v[4] = {acc[H][c][0], acc[H][c][1], acc[H][c][2], acc[H][c][3]};
      split4(v, Bhi[H][c], Blo[H][c]);
    }
  facc n[2][2];
#pragma unroll
  for (int R = 0; R < 2; ++R)
#pragma unroll
    for (int c = 0; c < 2; ++c) {
      facc z;
#pragma unroll
      for (int j = 0; j < 4; ++j) z[j] = 0.0f;
#pragma unroll
      for (int H = 0; H < 2; ++H) {
        z = MFMA16(Ahi[R][H], Bhi[H][c], z);
        z = MFMA16(Ahi[R][H], Blo[H][c], z);
        z = MFMA16(Alo[R][H], Bhi[H][c], z);
      }
      n[R][c] = z;
    }
#pragma unroll
  for (int R = 0; R < 2; ++R)
#pragma unroll
    for (int c = 0; c < 2; ++c) acc[R][c] = n[R][c];
}

// ---------------------------------------------------------------------------
// Fused kernel: 512 blocks x 512 threads (all co-resident: LDS 36.9KB->4/CU,
// VGPR<=128 -> 2/CU, grid = 2*256). Regular launch; manual barriers.
// ---------------------------------------------------------------------------
__global__ __launch_bounds__(512, 4) void fused_k(const float* __restrict__ x,
                                                  const float* __restrict__ core,
                                                  const float* __restrict__ label,
                                                  unsigned* __restrict__ core2b,
                                                  float* __restrict__ halfbuf,
                                                  unsigned* __restrict__ ctrs,
                                                  float* __restrict__ out) {
  const int tid = threadIdx.x;
  const int bid = blockIdx.x;  // 0..511
  __shared__ float smX[8][32 * 36];

  // ================= Phase 0: core -> core2b (r9 xform body) ================
  {
    const int gtid = bid * 512 + tid;  // 0..262143
    for (int idx = gtid; idx < 784 * 512; idx += 512 * 512) {
      const int s = idx >> 9;
      const int v = idx & 511;
      const float4 f = ((const float4*)(core + (size_t)s * 2048))[v];
      unsigned* dst = core2b + (size_t)s * 1024;
      int i = v >> 4;
      int c = (v & 15) * 2;
      int r = i >> 4, col16 = i & 15;
      int h2 = c >> 4, cl = c & 15;
      int q = cl >> 2, j = cl & 3;  // j in {0,2}
      float e0a = f.x - ((i == c) ? 1.0f : 0.0f);
      float e0b = f.z - ((i == c + 1) ? 1.0f : 0.0f);
      unsigned wa = ((unsigned)(unsigned short)bf16h(f.y - f.x) << 16) |
                    (unsigned)(unsigned short)bf16h(e0a);
      unsigned wb = ((unsigned)(unsigned short)bf16h(f.w - f.z) << 16) |
                    (unsigned)(unsigned short)bf16h(e0b);
      int di = ((r * 2 + h2) * 64 + 16 * q + col16) * 4 + j;
      *(uint2*)(dst + di) = make_uint2(wa, wb);
    }
  }

  // ---- manual grid barrier (agent-scope; all 512 blocks co-resident) ----
  __threadfence();     // release this thread's phase-0 stores agent-wide
  __syncthreads();
  if (tid == 0) {
    __hip_atomic_fetch_add(&ctrs[0], 1u, __ATOMIC_ACQ_REL, __HIP_MEMORY_SCOPE_AGENT);
    int guard = 0;
    while (__hip_atomic_load(&ctrs[0], __ATOMIC_RELAXED, __HIP_MEMORY_SCOPE_AGENT) <
           NBLK) {
      S_SLEEP();
      if (++guard > (1 << 22)) break;  // bounded: never hang the harness
    }
  }
  __syncthreads();
  __threadfence();     // acquire: invalidate stale caches before phase 1

  // ================= Phase 1: kchain (r9 body, verified) ====================
  {
    const int lane = tid & 63;
    const int k = tid >> 6;  // wave 0..7
    const int col16 = lane & 15;
    const int q = lane >> 4;

    const int chain = bid >> 1;   // 0..255 = b*2 + hside
    const int half = bid & 1;
    const int b = chain >> 1;
    const int hside = chain & 1;

    const int t = half * 8 + k;  // global segment 0..15
    const int start = (t < 8) ? 25 * t : 200 + 24 * (t - 8);
    const int len = (t < 8) ? 25 : 24;
    const int s_lo = hside * 392 + start;
    const int s_hi = s_lo + len - 1;

    facc acc[2][2];
#pragma unroll
    for (int r = 0; r < 2; ++r)
#pragma unroll
      for (int c = 0; c < 2; ++c)
#pragma unroll
        for (int j = 0; j < 4; ++j)
          acc[r][c][j] = (16 * r + 4 * q + j == 16 * c + col16) ? 1.0f : 0.0f;

    const uint4* cp = (const uint4*)core2b;
    const float* xb = x + b * 784;

    for (int s = s_hi; s >= s_lo; --s) {
      uint4 raw[4];  // frag f = r*2+h2
#pragma unroll
      for (int f = 0; f < 4; ++f) raw[f] = cp[(size_t)s * 256 + f * 64 + lane];
      const float xv = xb[s];

      // B = bf16(P_old) BEFORE accumulation (C/D layout == B layout, K=16)
      bfrag B[2][2];
#pragma unroll
      for (int h2 = 0; h2 < 2; ++h2)
#pragma unroll
        for (int c = 0; c < 2; ++c) B[h2][c] = pack4(acc[h2][c]);

      bfrag A[2][2];
#pragma unroll
      for (int r = 0; r < 2; ++r)
#pragma unroll
        for (int h2 = 0; h2 < 2; ++h2) {
          unsigned wd[4] = {raw[r * 2 + h2].x, raw[r * 2 + h2].y, raw[r * 2 + h2].z,
                            raw[r * 2 + h2].w};
          float e[4];
#pragma unroll
          for (int j = 0; j < 4; ++j) {
            float e0 = __uint_as_float(wd[j] << 16);
            float d = __uint_as_float(wd[j] & 0xFFFF0000u);
            e[j] = fmaf(xv, d, e0);
          }
          A[r][h2] = packf4(e[0], e[1], e[2], e[3]);
        }

#pragma unroll
      for (int r = 0; r < 2; ++r)
#pragma unroll
        for (int c = 0; c < 2; ++c) {
          acc[r][c] = MFMA16(A[r][0], B[0][c], acc[r][c]);
          acc[r][c] = MFMA16(A[r][1], B[1][c], acc[r][c]);
        }
    }

    // publish T_k = S_t^T row-major (fragment-level transpose, f4 store)
#pragma unroll
    for (int r = 0; r < 2; ++r)
#pragma unroll
      for (int c = 0; c < 2; ++c)
        *(float4*)&smX[k][(16 * c + col16) * 36 + 16 * r + 4 * q] =
            make_float4(acc[r][c][0], acc[r][c][1], acc[r][c][2], acc[r][c][3]);
    __syncthreads();

    facc a2[2][2];
#pragma unroll
    for (int r = 0; r < 2; ++r)
#pragma unroll
      for (int c = 0; c < 2; ++c)
#pragma unroll
        for (int j = 0; j < 4; ++j)
          a2[r][c][j] = (16 * r + 4 * q + j == 16 * c + col16) ? 1.0f : 0.0f;

    const int fo0 = (16 * 0 + col16) * 36 + 4 * q;
    const int fo1 = (16 * 1 + col16) * 36 + 4 * q;

    // L1: even waves fold pair (k, k+1): a2 = T_{k+1} * T_k
    if ((k & 1) == 0) {
      float4 av[2][2];
#pragma unroll
      for (int R = 0; R < 2; ++R)
#pragma unroll
        for (int H = 0; H < 2; ++H)
          av[R][H] = *(const float4*)&smX[k][(R ? fo1 : fo0) + 16 * H];
      fold_step(a2, av);  // = T_k
#pragma unroll
      for (int R = 0; R < 2; ++R)
#pragma unroll
        for (int H = 0; H < 2; ++H)
          av[R][H] = *(const float4*)&smX[k + 1][(R ? fo1 : fo0) + 16 * H];
      fold_step(a2, av);  // = T_{k+1} T_k
    }
    __syncthreads();
    if (k == 2 || k == 6) {
#pragma unroll
      for (int r = 0; r < 2; ++r)
#pragma unroll
        for (int c = 0; c < 2; ++c)
#pragma unroll
          for (int j = 0; j < 4; ++j)
            smX[k][(16 * r + 4 * q + j) * 36 + 16 * c + col16] = a2[r][c][j];
    }
    __syncthreads();
    if (k == 0 || k == 4) {
      float4 av[2][2];
#pragma unroll
      for (int R = 0; R < 2; ++R)
#pragma unroll
        for (int H = 0; H < 2; ++H)
          av[R][H] = *(const float4*)&smX[k + 2][(R ? fo1 : fo0) + 16 * H];
      fold_step(a2, av);  // = T_{k+3..k}
    }
    __syncthreads();
    if (k == 4) {
#pragma unroll
      for (int r = 0; r < 2; ++r)
#pragma unroll
        for (int c = 0; c < 2; ++c)
#pragma unroll
          for (int j = 0; j < 4; ++j)
            smX[4][(16 * r + 4 * q + j) * 36 + 16 * c + col16] = a2[r][c][j];
    }
    __syncthreads();
    // L3 + tail: wave 0 only (other waves exit; LDS lives while wave0 runs)
    if (k == 0) {
      float4 av[2][2];
#pragma unroll
      for (int R = 0; R < 2; ++R)
#pragma unroll
        for (int H = 0; H < 2; ++H)
          av[R][H] = *(const float4*)&smX[4][(R ? fo1 : fo0) + 16 * H];
      fold_step(a2, av);
      float* rm = halfbuf + (size_t)bid * 1024;  // bid = chain*2 + half
#pragma unroll
      for (int r = 0; r < 2; ++r)
#pragma unroll
        for (int c = 0; c < 2; ++c)
#pragma unroll
          for (int j = 0; j < 4; ++j)
            rm[(16 * r + 4 * q + j) * 32 + 16 * c + col16] = a2[r][c][j];

      // ---- last-arrival gate: 4 producer blocks per batch (bids 4b..4b+3) --
      __threadfence();  // release halfbuf stores (all lanes of wave 0)
      unsigned old = 0;
      if (lane == 0)
        old = __hip_atomic_fetch_add(&ctrs[1 + b], 1u, __ATOMIC_ACQ_REL,
                                     __HIP_MEMORY_SCOPE_AGENT);
      old = __shfl(old, 0, 64);
      if (old == 3u) {
        __threadfence();  // acquire the other 3 blocks' halfbuf stores

        // ============ Phase 2: gfin (r9 math, LDS-free) ====================
        facc hacc[2][2];
#pragma unroll
        for (int r = 0; r < 2; ++r)
#pragma unroll
          for (int c = 0; c < 2; ++c)
#pragma unroll
            for (int j = 0; j < 4; ++j)
              hacc[r][c][j] = (16 * r + 4 * q + j == 16 * c + col16) ? 1.0f : 0.0f;

        // fold order: X_R0, X_R1, X_L0, X_L1  (slot = chain*2 + half)
        const int slots[4] = {(2 * b + 1) * 2 + 0, (2 * b + 1) * 2 + 1,
                              (2 * b) * 2 + 0, (2 * b) * 2 + 1};
#pragma unroll
        for (int m = 0; m < 4; ++m) {
          const float* rm2 = halfbuf + (size_t)slots[m] * 1024;
          float4 qv[2][2];
#pragma unroll
          for (int R = 0; R < 2; ++R)
#pragma unroll
            for (int H = 0; H < 2; ++H)
              qv[R][H] =
                  *(const float4*)&rm2[(16 * R + col16) * 32 + 16 * H + 4 * q];
          fold_step(hacc, qv);
        }

        // hacc = H (C/D layout): lane holds H[16r+4q+j][16c+col16].
        // score[l] = sum H[row][col] * label[(row*32+col)*10 + l]
        float part[10];
#pragma unroll
        for (int l = 0; l < 10; ++l) part[l] = 0.0f;
#pragma unroll
        for (int r = 0; r < 2; ++r)
#pragma unroll
          for (int c = 0; c < 2; ++c)
#pragma unroll
            for (int j = 0; j < 4; ++j) {
              float v = hacc[r][c][j];
              const float* lb =
                  label + (size_t)((16 * r + 4 * q + j) * 32 + 16 * c + col16) * 10;
#pragma unroll
              for (int l = 0; l < 10; ++l) part[l] += v * lb[l];
            }
#pragma unroll
        for (int l = 0; l < 10; ++l) {
#pragma unroll
          for (int o = 32; o > 0; o >>= 1) part[l] += __shfl_xor(part[l], o, 64);
        }
        if (lane == 0) {
#pragma unroll
          for (int l = 0; l < 10; ++l) out[b * 10 + l] = part[l];
        }
      }
    }
  }
}

extern "C" void kernel_launch(void* const* d_in, const int* in_sizes, int n_in,
                              void* d_out, int out_size, void* d_ws, size_t ws_size,
                              hipStream_t stream) {
  const float* x = (const float*)d_in[0];      // (128, 784)
  const float* core = (const float*)d_in[1];   // (784, 32, 32, 2)
  const float* label = (const float*)d_in[2];  // (32, 32, 10)
  float* out = (float*)d_out;                  // (128, 10)

  unsigned* core2b = (unsigned*)d_ws;                       // 3.2 MB
  float* halfbuf = (float*)d_ws + CORE2B_DWORDS;            // 2 MB
  unsigned* ctrs = (unsigned*)d_ws + CTR_DWORD_OFF;         // 516 B

  hipMemsetAsync(ctrs, 0, (1 + 128) * sizeof(unsigned), stream);
  hipLaunchKernelGGL(fused_k, dim3(512), dim3(512), 0, stream, x, core, label,
                     core2b, halfbuf, ctrs, out);
}

// Round 14
// 120.207 us; speedup vs baseline: 2.3638x; 2.3638x over previous
//
#include <hip/hip_runtime.h>
#include <cstddef>

// MPS classifier: SIZE=784, D=32, DLOC=2, NUM_LABELS=10, LABEL_SITE=392, B=128
//
// Round-14 = round-9 (93.25us, best) + gfin folded into kchain's tail via the
// r13-VALIDATED last-arrival gate (the only piece of r13 that was cheap AND
// correct; the 512-block spin barrier cost ~200us and is gone).
//  - xform_k: r9 verbatim (core -> core2b bf16 pairs, fragment-major).
//  - kchain: r9 verbatim (8 segment waves + 3-level T-world LDS tree fold);
//    wave 0, after storing halfbuf slot: threadfence -> atomicAdd(ctr[b]);
//    the 4th arriving block (old==3) acquires and runs the LDS-free gfin
//    (4 fold_steps + register label contraction + shfl reduce) for batch b.
//  - ctrs (128 dwords) zeroed by a tiny hipMemsetAsync node (poison-proof).
// ws: [core2b 3.2MB][halfbuf 2MB][ctrs 512B].

typedef short bfrag __attribute__((ext_vector_type(4)));   // 4 bf16
typedef float facc  __attribute__((ext_vector_type(4)));   // 4 fp32

#if !defined(__HIP_DEVICE_COMPILE__)
#define MFMA16(a, b, c) (c)  // host-pass stub (host clang lacks amdgcn builtins)
#elif __has_builtin(__builtin_amdgcn_mfma_f32_16x16x16bf16_1k)
#define MFMA16(a, b, c) __builtin_amdgcn_mfma_f32_16x16x16bf16_1k(a, b, c, 0, 0, 0)
#elif __has_builtin(__builtin_amdgcn_mfma_f32_16x16x16_bf16)
#define MFMA16(a, b, c) __builtin_amdgcn_mfma_f32_16x16x16_bf16(a, b, c, 0, 0, 0)
#else
#error "no 16x16x16 bf16 MFMA builtin on this target"
#endif

#define CORE2B_DWORDS (784 * 1024)
#define HALF_FLOATS (512 * 1024)
#define CTR_DWORD_OFF (CORE2B_DWORDS + HALF_FLOATS)

__device__ __forceinline__ short bf16h(float v) {
  unsigned u = __float_as_uint(v) + 0x8000u;  // round-half-up to bf16
  return (short)(u >> 16);
}

// pack 4 fp32 -> 4 bf16 (HW cvt_pk on gfx950, manual fallback)
#if defined(__HIP_DEVICE_COMPILE__) && __has_builtin(__builtin_amdgcn_cvt_pk_bf16_f32)
typedef __bf16 bf16x2 __attribute__((ext_vector_type(2)));
__device__ __forceinline__ bfrag packf4(float a, float b, float c, float d) {
  bf16x2 lo = __builtin_amdgcn_cvt_pk_bf16_f32(a, b);
  bf16x2 hi = __builtin_amdgcn_cvt_pk_bf16_f32(c, d);
  uint2 u = make_uint2(__builtin_bit_cast(unsigned, lo), __builtin_bit_cast(unsigned, hi));
  return __builtin_bit_cast(bfrag, u);
}
#else
__device__ __forceinline__ bfrag packf4(float a, float b, float c, float d) {
  bfrag r; r[0] = bf16h(a); r[1] = bf16h(b); r[2] = bf16h(c); r[3] = bf16h(d);
  return r;
}
#endif

__device__ __forceinline__ bfrag pack4(const facc v) {
  return packf4(v[0], v[1], v[2], v[3]);
}

// fp32 -> (hi bf16 rounded, lo bf16 of remainder) — folds only
__device__ __forceinline__ void split4(const float* v, bfrag& hi, bfrag& lo) {
#pragma unroll
  for (int j = 0; j < 4; ++j) {
    unsigned u = (__float_as_uint(v[j]) + 0x8000u) & 0xFFFF0000u;
    hi[j] = (short)(u >> 16);
    float lf = v[j] - __uint_as_float(u);
    lo[j] = bf16h(lf);
  }
}

// One fold step: acc <- A * acc (3-term bf16 hi/lo split).
// av[R][H] = float4 A-frag: A[16R+col16][16H+4q .. +3].
__device__ __forceinline__ void fold_step(facc (&acc)[2][2], const float4 (&av)[2][2]) {
  bfrag Ahi[2][2], Alo[2][2], Bhi[2][2], Blo[2][2];
#pragma unroll
  for (int R = 0; R < 2; ++R)
#pragma unroll
    for (int H = 0; H < 2; ++H) {
      float v[4] = {av[R][H].x, av[R][H].y, av[R][H].z, av[R][H].w};
      split4(v, Ahi[R][H], Alo[R][H]);
    }
#pragma unroll
  for (int H = 0; H < 2; ++H)
#pragma unroll
    for (int c = 0; c < 2; ++c) {
      float v[4] = {acc[H][c][0], acc[H][c][1], acc[H][c][2], acc[H][c][3]};
      split4(v, Bhi[H][c], Blo[H][c]);
    }
  facc n[2][2];
#pragma unroll
  for (int R = 0; R < 2; ++R)
#pragma unroll
    for (int c = 0; c < 2; ++c) {
      facc z;
#pragma unroll
      for (int j = 0; j < 4; ++j) z[j] = 0.0f;
#pragma unroll
      for (int H = 0; H < 2; ++H) {
        z = MFMA16(Ahi[R][H], Bhi[H][c], z);
        z = MFMA16(Ahi[R][H], Blo[H][c], z);
        z = MFMA16(Alo[R][H], Bhi[H][c], z);
      }
      n[R][c] = z;
    }
#pragma unroll
  for (int R = 0; R < 2; ++R)
#pragma unroll
    for (int c = 0; c < 2; ++c) acc[R][c] = n[R][c];
}

// ---------------------------------------------------------------------------
// K0: core -> core2b (r9 verbatim). Coalesced reads, scattered 8B writes.
// ---------------------------------------------------------------------------
__global__ __launch_bounds__(256) void xform_k(const float* __restrict__ core,
                                               unsigned* __restrict__ core2b) {
  const int s = blockIdx.x;  // 0..783
  const int tid = threadIdx.x;
  const float4* src = (const float4*)(core + (size_t)s * 2048);
  unsigned* dst = core2b + (size_t)s * 1024;
#pragma unroll
  for (int u = 0; u < 2; ++u) {
    int v = tid + 256 * u;  // 0..511, coalesced
    float4 f = src[v];
    int i = v >> 4;
    int c = (v & 15) * 2;
    int r = i >> 4, col16 = i & 15;
    int h2 = c >> 4, cl = c & 15;
    int q = cl >> 2, j = cl & 3;  // j in {0,2}
    float e0a = f.x - ((i == c) ? 1.0f : 0.0f);
    float e0b = f.z - ((i == c + 1) ? 1.0f : 0.0f);
    unsigned wa = ((unsigned)(unsigned short)bf16h(f.y - f.x) << 16) |
                  (unsigned)(unsigned short)bf16h(e0a);
    unsigned wb = ((unsigned)(unsigned short)bf16h(f.w - f.z) << 16) |
                  (unsigned)(unsigned short)bf16h(e0b);
    int idx = ((r * 2 + h2) * 64 + 16 * q + col16) * 4 + j;
    *(uint2*)(dst + idx) = make_uint2(wa, wb);
  }
}

// ---------------------------------------------------------------------------
// K1 kchain: 512 blocks x 512 thr (r9 verbatim) + last-arrival gfin tail.
// bid = chain*2 + half; batch b has producer bids {4b, 4b+1, 4b+2, 4b+3}.
// ---------------------------------------------------------------------------
__global__ __launch_bounds__(512, 4) void kchain(const float* __restrict__ x,
                                                 const unsigned* __restrict__ core2b,
                                                 float* __restrict__ halfbuf,
                                                 unsigned* __restrict__ ctrs,
                                                 const float* __restrict__ label,
                                                 float* __restrict__ out) {
  const int tid = threadIdx.x;
  const int lane = tid & 63;
  const int k = tid >> 6;  // wave 0..7
  const int col16 = lane & 15;
  const int q = lane >> 4;

  const int bid = blockIdx.x;   // 0..511
  const int chain = bid >> 1;   // 0..255 = b*2 + hside
  const int half = bid & 1;
  const int b = chain >> 1;
  const int hside = chain & 1;

  const int t = half * 8 + k;  // global segment 0..15
  const int start = (t < 8) ? 25 * t : 200 + 24 * (t - 8);
  const int len = (t < 8) ? 25 : 24;
  const int s_lo = hside * 392 + start;
  const int s_hi = s_lo + len - 1;

  __shared__ float smX[8][32 * 36];  // padded row-major slots (stride 36)

  facc acc[2][2];
#pragma unroll
  for (int r = 0; r < 2; ++r)
#pragma unroll
    for (int c = 0; c < 2; ++c)
#pragma unroll
      for (int j = 0; j < 4; ++j)
        acc[r][c][j] = (16 * r + 4 * q + j == 16 * c + col16) ? 1.0f : 0.0f;

  const uint4* cp = (const uint4*)core2b;
  const float* xb = x + b * 784;

  // ---- segment site loop (r9-verified): acc = S_t (C/D layout) ----
  for (int s = s_hi; s >= s_lo; --s) {
    uint4 raw[4];  // frag f = r*2+h2
#pragma unroll
    for (int f = 0; f < 4; ++f) raw[f] = cp[(size_t)s * 256 + f * 64 + lane];
    const float xv = xb[s];

    // B = bf16(P_old) BEFORE accumulation (C/D layout == B layout, K=16)
    bfrag B[2][2];
#pragma unroll
    for (int h2 = 0; h2 < 2; ++h2)
#pragma unroll
      for (int c = 0; c < 2; ++c) B[h2][c] = pack4(acc[h2][c]);

    bfrag A[2][2];
#pragma unroll
    for (int r = 0; r < 2; ++r)
#pragma unroll
      for (int h2 = 0; h2 < 2; ++h2) {
        unsigned wd[4] = {raw[r * 2 + h2].x, raw[r * 2 + h2].y, raw[r * 2 + h2].z,
                          raw[r * 2 + h2].w};
        float e[4];
#pragma unroll
        for (int j = 0; j < 4; ++j) {
          float e0 = __uint_as_float(wd[j] << 16);
          float d = __uint_as_float(wd[j] & 0xFFFF0000u);
          e[j] = fmaf(xv, d, e0);
        }
        A[r][h2] = packf4(e[0], e[1], e[2], e[3]);
      }

#pragma unroll
    for (int r = 0; r < 2; ++r)
#pragma unroll
      for (int c = 0; c < 2; ++c) {
        acc[r][c] = MFMA16(A[r][0], B[0][c], acc[r][c]);
        acc[r][c] = MFMA16(A[r][1], B[1][c], acc[r][c]);
      }
  }

  // ---- publish T_k = S_t^T row-major (fragment-level transpose, f4 store) ----
#pragma unroll
  for (int r = 0; r < 2; ++r)
#pragma unroll
    for (int c = 0; c < 2; ++c)
      *(float4*)&smX[k][(16 * c + col16) * 36 + 16 * r + 4 * q] =
          make_float4(acc[r][c][0], acc[r][c][1], acc[r][c][2], acc[r][c][3]);
  __syncthreads();

  facc a2[2][2];
#pragma unroll
  for (int r = 0; r < 2; ++r)
#pragma unroll
    for (int c = 0; c < 2; ++c)
#pragma unroll
      for (int j = 0; j < 4; ++j)
        a2[r][c][j] = (16 * r + 4 * q + j == 16 * c + col16) ? 1.0f : 0.0f;

  const int fo0 = (16 * 0 + col16) * 36 + 4 * q;
  const int fo1 = (16 * 1 + col16) * 36 + 4 * q;

  // L1: even waves fold pair (k, k+1): a2 = T_{k+1} * T_k
  if ((k & 1) == 0) {
    float4 av[2][2];
#pragma unroll
    for (int R = 0; R < 2; ++R)
#pragma unroll
      for (int H = 0; H < 2; ++H)
        av[R][H] = *(const float4*)&smX[k][(R ? fo1 : fo0) + 16 * H];
    fold_step(a2, av);  // = T_k
#pragma unroll
    for (int R = 0; R < 2; ++R)
#pragma unroll
      for (int H = 0; H < 2; ++H)
        av[R][H] = *(const float4*)&smX[k + 1][(R ? fo1 : fo0) + 16 * H];
    fold_step(a2, av);  // = T_{k+1} T_k
  }
  __syncthreads();
  if (k == 2 || k == 6) {
#pragma unroll
    for (int r = 0; r < 2; ++r)
#pragma unroll
      for (int c = 0; c < 2; ++c)
#pragma unroll
        for (int j = 0; j < 4; ++j)
          smX[k][(16 * r + 4 * q + j) * 36 + 16 * c + col16] = a2[r][c][j];
  }
  __syncthreads();
  if (k == 0 || k == 4) {
    float4 av[2][2];
#pragma unroll
    for (int R = 0; R < 2; ++R)
#pragma unroll
      for (int H = 0; H < 2; ++H)
        av[R][H] = *(const float4*)&smX[k + 2][(R ? fo1 : fo0) + 16 * H];
    fold_step(a2, av);  // = T_{k+3..k}
  }
  __syncthreads();
  if (k == 4) {
#pragma unroll
    for (int r = 0; r < 2; ++r)
#pragma unroll
      for (int c = 0; c < 2; ++c)
#pragma unroll
        for (int j = 0; j < 4; ++j)
          smX[4][(16 * r + 4 * q + j) * 36 + 16 * c + col16] = a2[r][c][j];
  }
  __syncthreads();
  // L3 + tail: wave 0 only
  if (k == 0) {
    float4 av[2][2];
#pragma unroll
    for (int R = 0; R < 2; ++R)
#pragma unroll
      for (int H = 0; H < 2; ++H)
        av[R][H] = *(const float4*)&smX[4][(R ? fo1 : fo0) + 16 * H];
    fold_step(a2, av);
    float* rm = halfbuf + (size_t)bid * 1024;  // bid = chain*2 + half
#pragma unroll
    for (int r = 0; r < 2; ++r)
#pragma unroll
      for (int c = 0; c < 2; ++c)
#pragma unroll
        for (int j = 0; j < 4; ++j)
          rm[(16 * r + 4 * q + j) * 32 + 16 * c + col16] = a2[r][c][j];

    // ---- last-arrival gate (r13-validated): 4 producer blocks per batch ----
    __threadfence();  // release halfbuf stores
    unsigned old = 0;
    if (lane == 0)
      old = __hip_atomic_fetch_add(&ctrs[b], 1u, __ATOMIC_ACQ_REL,
                                   __HIP_MEMORY_SCOPE_AGENT);
    old = __shfl(old, 0, 64);
    if (old == 3u) {
      __threadfence();  // acquire the other 3 blocks' halfbuf stores

      // ---- gfin (r13-validated, LDS-free) ----
      facc hacc[2][2];
#pragma unroll
      for (int r = 0; r < 2; ++r)
#pragma unroll
        for (int c = 0; c < 2; ++c)
#pragma unroll
          for (int j = 0; j < 4; ++j)
            hacc[r][c][j] = (16 * r + 4 * q + j == 16 * c + col16) ? 1.0f : 0.0f;

      // fold order: X_R0, X_R1, X_L0, X_L1  (slot = chain*2 + half)
      const int slots[4] = {(2 * b + 1) * 2 + 0, (2 * b + 1) * 2 + 1,
                            (2 * b) * 2 + 0, (2 * b) * 2 + 1};
#pragma unroll
      for (int m = 0; m < 4; ++m) {
        const float* rm2 = halfbuf + (size_t)slots[m] * 1024;
        float4 qv[2][2];
#pragma unroll
        for (int R = 0; R < 2; ++R)
#pragma unroll
          for (int H = 0; H < 2; ++H)
            qv[R][H] = *(const float4*)&rm2[(16 * R + col16) * 32 + 16 * H + 4 * q];
        fold_step(hacc, qv);
      }

      // hacc = H (C/D layout): lane holds H[16r+4q+j][16c+col16].
      float part[10];
#pragma unroll
      for (int l = 0; l < 10; ++l) part[l] = 0.0f;
#pragma unroll
      for (int r = 0; r < 2; ++r)
#pragma unroll
        for (int c = 0; c < 2; ++c)
#pragma unroll
          for (int j = 0; j < 4; ++j) {
            float v = hacc[r][c][j];
            const float* lb =
                label + (size_t)((16 * r + 4 * q + j) * 32 + 16 * c + col16) * 10;
#pragma unroll
            for (int l = 0; l < 10; ++l) part[l] += v * lb[l];
          }
#pragma unroll
      for (int l = 0; l < 10; ++l) {
#pragma unroll
        for (int o = 32; o > 0; o >>= 1) part[l] += __shfl_xor(part[l], o, 64);
      }
      if (lane == 0) {
#pragma unroll
        for (int l = 0; l < 10; ++l) out[b * 10 + l] = part[l];
      }
    }
  }
}

extern "C" void kernel_launch(void* const* d_in, const int* in_sizes, int n_in,
                              void* d_out, int out_size, void* d_ws, size_t ws_size,
                              hipStream_t stream) {
  const float* x = (const float*)d_in[0];      // (128, 784)
  const float* core = (const float*)d_in[1];   // (784, 32, 32, 2)
  const float* label = (const float*)d_in[2];  // (32, 32, 10)
  float* out = (float*)d_out;                  // (128, 10)

  unsigned* core2b = (unsigned*)d_ws;                 // 3.2 MB
  float* halfbuf = (float*)d_ws + CORE2B_DWORDS;      // 2 MB
  unsigned* ctrs = (unsigned*)d_ws + CTR_DWORD_OFF;   // 512 B

  hipMemsetAsync(ctrs, 0, 128 * sizeof(unsigned), stream);
  hipLaunchKernelGGL(xform_k, dim3(784), dim3(256), 0, stream, core, core2b);
  hipLaunchKernelGGL(kchain, dim3(512), dim3(512), 0, stream, x, core2b, halfbuf,
                     ctrs, label, out);
}